// Round 9
// baseline (175.249 us; speedup 1.0000x reference)
//
#include <hip/hip_runtime.h>
#include <math.h>

#define B_  16
#define C_  512
#define A_  64
#define CV  448     // C - A (value / z_img dims)
#define G_  256
#define HW  256
#define SMX 256     // padded S (Smax)
#define SLICE 64    // s-rows per score block
#define BSP 8       // b-rows per pv block
#define SH  128     // s-rows per pv block

// ---------------- K1: mean pool + per-group size + zero Msnd -----------------
__global__ __launch_bounds__(256) void meanpool_kernel(const float* __restrict__ Zimg,
                                                       float* __restrict__ z,
                                                       const int* __restrict__ pad_idx,
                                                       int* __restrict__ sgArr,
                                                       float* __restrict__ Msnd,
                                                       int Smax, int N) {
  const int bid = blockIdx.x, t = threadIdx.x;
  const int lane = t & 63, wave = t >> 6;
  __shared__ int r4[4];

  if (t < 224)                          // 2048 blocks x 896 floats = Msnd (7.3 MB)
    *(float4*)(Msnd + (size_t)bid * 896 + t * 4) = make_float4(0.f, 0.f, 0.f, 0.f);

  if (bid < G_) {                       // group size (prefix-contiguous validity)
    int v = pad_idx[(size_t)bid * Smax + t];
    bool ok = ((t == 0) || (v != 0)) && (v >= 0) && (v < N);
    int sgv = ok ? (t + 1) : 0;
    #pragma unroll
    for (int off = 32; off > 0; off >>= 1)
      sgv = max(sgv, __shfl_xor(sgv, off, 64));
    if (lane == 0) r4[wave] = sgv;
    __syncthreads();
    if (t == 0) sgArr[bid] = max(max(r4[0], r4[1]), max(r4[2], r4[3]));
  }

  int row = (bid << 2) + (t >> 6);      // b*C + c
  const float4* p = (const float4*)(Zimg + (size_t)row * HW);
  float4 v = p[lane];
  float s = (v.x + v.y) + (v.z + v.w);
  #pragma unroll
  for (int off = 32; off > 0; off >>= 1)
    s += __shfl_down(s, off, 64);
  if (lane == 0) z[row] = s * (1.0f / HW);
}

// ---------------- K2: scores[g][s][b] for a 64-s slice (r3-proven) -----------
// grid = G_*4, 256 thr. thread = (s_l = t>>2, kq = t&3): 16-dim quarter dot
// for all 16 b, combined via shfl_xor(1,2). Invalid s -> -INF row.
__global__ __launch_bounds__(256, 4) void score_kernel(
    const float* __restrict__ Zsnd,
    const int*   __restrict__ pad_idx,
    const float* __restrict__ z,
    float*       __restrict__ scores,
    int Smax, int N)
{
  const int bid = blockIdx.x;
  const int g   = bid >> 2;
  const int s0  = (bid & 3) * SLICE;
  const int t   = threadIdx.x;

  __shared__ float qs[B_ * A_];     // 4 KB
  __shared__ int   idx[SLICE];

  if (t < SLICE) {
    int s = s0 + t;
    int v = (s < Smax) ? pad_idx[(size_t)g * Smax + s] : 0;
    bool ok = (s < Smax) && ((s == 0) || (v != 0)) && (v >= 0) && (v < N);
    idx[t] = ok ? v : -1;
  }
  { int b = t >> 4, a4 = t & 15;    // 16 b x 16 float4 = 256 threads
    *(float4*)(qs + b * A_ + a4 * 4) =
        *(const float4*)(z + b * C_ + CV + a4 * 4); }
  __syncthreads();

  const int s_l = t >> 2, kq = t & 3;
  const int my  = idx[s_l];

  float sc[B_];
  #pragma unroll
  for (int b = 0; b < B_; b++) sc[b] = 0.0f;

  if (my >= 0) {
    const float* kr = Zsnd + (size_t)my * C_ + CV + kq * 16;
    float4 k0 = *(const float4*)(kr + 0);
    float4 k1 = *(const float4*)(kr + 4);
    float4 k2 = *(const float4*)(kr + 8);
    float4 k3 = *(const float4*)(kr + 12);
    #pragma unroll
    for (int b = 0; b < B_; b++) {
      const float* qb = qs + b * A_ + kq * 16;
      float4 q0 = *(const float4*)(qb + 0);
      float4 q1 = *(const float4*)(qb + 4);
      float4 q2 = *(const float4*)(qb + 8);
      float4 q3 = *(const float4*)(qb + 12);
      sc[b] = q0.x * k0.x + q0.y * k0.y + q0.z * k0.z + q0.w * k0.w
            + q1.x * k1.x + q1.y * k1.y + q1.z * k1.z + q1.w * k1.w
            + q2.x * k2.x + q2.y * k2.y + q2.z * k2.z + q2.w * k2.w
            + q3.x * k3.x + q3.y * k3.y + q3.z * k3.z + q3.w * k3.w;
    }
  }
  #pragma unroll
  for (int b = 0; b < B_; b++) {
    sc[b] += __shfl_xor(sc[b], 1, 64);
    sc[b] += __shfl_xor(sc[b], 2, 64);
  }
  if (kq == 0) {
    float* out = scores + ((size_t)g * SMX + s0 + s_l) * B_;
    if (my >= 0) {
      *(float4*)(out + 0)  = make_float4(sc[0],  sc[1],  sc[2],  sc[3]);
      *(float4*)(out + 4)  = make_float4(sc[4],  sc[5],  sc[6],  sc[7]);
      *(float4*)(out + 8)  = make_float4(sc[8],  sc[9],  sc[10], sc[11]);
      *(float4*)(out + 12) = make_float4(sc[12], sc[13], sc[14], sc[15]);
    } else {
      float4 ninf = make_float4(-INFINITY, -INFINITY, -INFINITY, -INFINITY);
      *(float4*)(out + 0) = ninf; *(float4*)(out + 4) = ninf;
      *(float4*)(out + 8) = ninf; *(float4*)(out + 12) = ninf;
    }
  }
}

// ---------------- K3: per-(g,b) softmax stats + Mimg broadcast (r3-proven) ---
__global__ __launch_bounds__(256) void stats_kernel(
    const float* __restrict__ scores,
    const float* __restrict__ z,
    float*       __restrict__ m_g,
    float*       __restrict__ l_g,
    float*       __restrict__ Mimg)
{
  const int g = blockIdx.x, t = threadIdx.x, lane = t & 63, wave = t >> 6;
  __shared__ float red[4][B_];
  __shared__ float red2[4][B_];

  const float* srow = scores + ((size_t)g * SMX + t) * B_;
  float sc[B_];
  #pragma unroll
  for (int i = 0; i < 4; i++) {
    float4 v = *(const float4*)(srow + i * 4);
    sc[i * 4 + 0] = v.x; sc[i * 4 + 1] = v.y; sc[i * 4 + 2] = v.z; sc[i * 4 + 3] = v.w;
  }
  #pragma unroll
  for (int b = 0; b < B_; b++) {
    float v = sc[b];
    #pragma unroll
    for (int off = 32; off > 0; off >>= 1)
      v = fmaxf(v, __shfl_xor(v, off, 64));
    if (lane == 0) red[wave][b] = v;
  }
  __syncthreads();
  #pragma unroll
  for (int b = 0; b < B_; b++) {
    float gm = fmaxf(fmaxf(red[0][b], red[1][b]), fmaxf(red[2][b], red[3][b]));
    float e  = __expf(sc[b] - gm);       // -INF rows -> 0
    #pragma unroll
    for (int off = 32; off > 0; off >>= 1)
      e += __shfl_xor(e, off, 64);
    if (lane == 0) red2[wave][b] = e;
  }
  __syncthreads();
  if (t < B_) {
    float gm = fmaxf(fmaxf(red[0][t], red[1][t]), fmaxf(red[2][t], red[3][t]));
    float gs = (red2[0][t] + red2[1][t]) + (red2[2][t] + red2[3][t]);
    m_g[g * B_ + t] = gm;
    l_g[g * B_ + t] = gs;
  }
  #pragma unroll
  for (int i = 0; i < 7; i++) {          // Mimg[g,b,:] = z[b,:CV]
    int li = i * 256 + t;
    int b = li / 112, c4 = li % 112;
    *(float4*)(Mimg + (size_t)g * (B_ * CV) + b * CV + c4 * 4) =
        *(const float4*)(z + b * C_ + c4 * 4);
  }
}

// ---------------- K4: PV for (g, b-half, s-half) -----------------------------
// grid = G_*4, 512 thr, 8 waves -> 4 blocks/CU = 32 waves (the r6-proven
// max-throughput regime) at HALF r6's value traffic (2x dup instead of 4x).
// bid = (g<<2)|(sh<<1)|bh: row-sharing blocks (bh0,bh1) are bid-adjacent ->
// same XCD L2 under both consecutive and round-robin dispatch.
// Weights recomputed from scores + (m,l); r1's v[8]/acc[8] gather pipeline;
// outputs via atomicAdd onto pre-zeroed Msnd (plain store when sg<=SH: block
// is the sole writer). Empty s-halves exit before any barrier.
__global__ __launch_bounds__(512, 4) void pv_kernel(
    const float* __restrict__ Zsnd,
    const int*   __restrict__ pad_idx,
    const float* __restrict__ scores,
    const float* __restrict__ m_g,
    const float* __restrict__ l_g,
    const int*   __restrict__ sgArr,
    float*       __restrict__ Msnd,
    int Smax, int N)
{
  const int bid = blockIdx.x;
  const int g   = bid >> 2;
  const int sh  = (bid >> 1) & 1;
  const int bh  = bid & 1;
  const int s0  = sh * SH;
  const int b0  = bh * BSP;
  const int t    = threadIdx.x;
  const int lane = t & 63;
  const int wave = t >> 6;

  __shared__ int   idxs[SH];                // 0.5 KB
  __shared__ float w[SH * BSP];             // 4 KB [s_l][b-local]
  __shared__ float mls[16];                 // m[0..7], 1/l[8..15]
  __shared__ float redS[4 * BSP * 64 * 4];  // 32 KB [ch][b][lane] float4

  const int sg = sgArr[g];
  const int nloc = min(SH, ((sg + 31) & ~31) - s0);
  if (nloc <= 0) return;                    // uniform: whole s-half empty

  if (t < SH) {
    int s = s0 + t;
    int v = pad_idx[(size_t)g * Smax + s];
    bool ok = ((s == 0) || (v != 0)) && (v >= 0) && (v < N);
    idxs[t] = ok ? v : 0;                   // weight is 0 for invalid s
  }
  if (t < 8) {
    mls[t]     = m_g[g * B_ + b0 + t];
    mls[8 + t] = 1.0f / l_g[g * B_ + b0 + t];
  }
  __syncthreads();

  {                                         // w: 128 s x 8 b; t = (s_l, bq)
    const int s_l = t >> 2, bq = t & 3;
    const float2 s2 = *(const float2*)(scores + ((size_t)g * SMX + s0 + s_l) * B_ + b0 + bq * 2);
    w[s_l * BSP + bq * 2 + 0] = __expf(s2.x - mls[bq * 2 + 0]) * mls[8 + bq * 2 + 0];
    w[s_l * BSP + bq * 2 + 1] = __expf(s2.y - mls[bq * 2 + 1]) * mls[8 + bq * 2 + 1];
  }
  __syncthreads();

  // ---- gather loop: waves (ch, sp); lanes (cl, h); 8 float4 in flight ----
  const int ch = wave >> 1;                 // column chunk (0..3)
  const int sp = wave & 1;                  // s parity
  const int cl = lane & 31;                 // float4 column slot
  const int h  = lane >> 5;                 // s sub-parity
  const int c0 = ch * 128;

  const float* vbase = Zsnd + c0 + cl * 4;  // + idx*C_ ; col <= 508 in-row
  float4 acc[BSP];
  #pragma unroll
  for (int b = 0; b < BSP; b++) acc[b] = make_float4(0.f, 0.f, 0.f, 0.f);

  for (int ss = 0; ss < nloc; ss += 32) {
    float4 v[8];
    #pragma unroll
    for (int j = 0; j < 8; j++) {
      int so = ss + 4 * j + 2 * sp + h;
      v[j] = *(const float4*)(vbase + (size_t)idxs[so] * C_);
    }
    #pragma unroll
    for (int j = 0; j < 8; j++) {
      int so = ss + 4 * j + 2 * sp + h;
      float4 w0 = *(const float4*)(w + so * BSP + 0);   // b 0..3 (broadcast)
      float4 w1 = *(const float4*)(w + so * BSP + 4);   // b 4..7
      float4 vv = v[j];
      acc[0].x += w0.x * vv.x; acc[0].y += w0.x * vv.y; acc[0].z += w0.x * vv.z; acc[0].w += w0.x * vv.w;
      acc[1].x += w0.y * vv.x; acc[1].y += w0.y * vv.y; acc[1].z += w0.y * vv.z; acc[1].w += w0.y * vv.w;
      acc[2].x += w0.z * vv.x; acc[2].y += w0.z * vv.y; acc[2].z += w0.z * vv.z; acc[2].w += w0.z * vv.w;
      acc[3].x += w0.w * vv.x; acc[3].y += w0.w * vv.y; acc[3].z += w0.w * vv.z; acc[3].w += w0.w * vv.w;
      acc[4].x += w1.x * vv.x; acc[4].y += w1.x * vv.y; acc[4].z += w1.x * vv.z; acc[4].w += w1.x * vv.w;
      acc[5].x += w1.y * vv.x; acc[5].y += w1.y * vv.y; acc[5].z += w1.y * vv.z; acc[5].w += w1.y * vv.w;
      acc[6].x += w1.z * vv.x; acc[6].y += w1.z * vv.y; acc[6].z += w1.z * vv.z; acc[6].w += w1.z * vv.w;
      acc[7].x += w1.w * vv.x; acc[7].y += w1.w * vv.y; acc[7].z += w1.w * vv.z; acc[7].w += w1.w * vv.w;
    }
  }

  // ---- cross-wave combine: sp==1 partials -> LDS, sp==0 adds + h-shfl ----
  if (sp == 1) {
    #pragma unroll
    for (int b = 0; b < BSP; b++)
      *(float4*)(redS + (((size_t)ch * BSP + b) * 64 + lane) * 4) = acc[b];
  }
  __syncthreads();
  if (sp == 0) {
    #pragma unroll
    for (int b = 0; b < BSP; b++) {
      float4 o = *(const float4*)(redS + (((size_t)ch * BSP + b) * 64 + lane) * 4);
      acc[b].x += o.x; acc[b].y += o.y; acc[b].z += o.z; acc[b].w += o.w;
      acc[b].x += __shfl_xor(acc[b].x, 32, 64);
      acc[b].y += __shfl_xor(acc[b].y, 32, 64);
      acc[b].z += __shfl_xor(acc[b].z, 32, 64);
      acc[b].w += __shfl_xor(acc[b].w, 32, 64);
    }
    if (h == 0 && c0 + cl * 4 < CV) {
      float* ob = Msnd + (size_t)g * (B_ * CV) + (size_t)b0 * CV + c0 + cl * 4;
      if (sg <= SH) {                       // sole writer: plain store
        #pragma unroll
        for (int b = 0; b < BSP; b++)
          *(float4*)(ob + b * CV) = acc[b];
      } else {                              // two s-halves: atomic combine
        #pragma unroll
        for (int b = 0; b < BSP; b++) {
          atomicAdd(ob + b * CV + 0, acc[b].x);
          atomicAdd(ob + b * CV + 1, acc[b].y);
          atomicAdd(ob + b * CV + 2, acc[b].z);
          atomicAdd(ob + b * CV + 3, acc[b].w);
        }
      }
    }
  }
}

extern "C" void kernel_launch(void* const* d_in, const int* in_sizes, int n_in,
                              void* d_out, int out_size, void* d_ws, size_t ws_size,
                              hipStream_t stream) {
  const float* Zimg   = (const float*)d_in[0];
  const float* Zsnd   = (const float*)d_in[1];
  const int*   padidx = (const int*)d_in[2];
  // d_in[3] = pad_mask (unused; validity derived from pad_idx)
  // d_in[4] = attn_dims (constant 64)

  const int N    = in_sizes[1] / C_;     // rows in Z_snd
  const int Smax = in_sizes[2] / G_;     // padded sequence length (== 256)

  float* z      = (float*)d_ws;                          // 8192 f32
  int*   sgArr  = (int*)(z + B_ * C_);                   // 256 ints
  float* scores = (float*)(sgArr + G_);                  // G*SMX*B = 4 MB
  float* m_g    = scores + (size_t)G_ * SMX * B_;        // 4096 f32
  float* l_g    = m_g + G_ * B_;                         // 4096 f32
  float* Mimg = (float*)d_out;
  float* Msnd = Mimg + (size_t)G_ * B_ * CV;

  meanpool_kernel<<<(B_ * C_) / 4, 256, 0, stream>>>(Zimg, z, padidx, sgArr, Msnd, Smax, N);
  score_kernel<<<G_ * 4, 256, 0, stream>>>(Zsnd, padidx, z, scores, Smax, N);
  stats_kernel<<<G_, 256, 0, stream>>>(scores, z, m_g, l_g, Mimg);
  pv_kernel<<<G_ * 4, 512, 0, stream>>>(Zsnd, padidx, scores, m_g, l_g, sgArr, Msnd, Smax, N);
}

// Round 10
// 146.929 us; speedup vs baseline: 1.1927x; 1.1927x over previous
//
#include <hip/hip_runtime.h>
#include <math.h>

#define B_  16
#define C_  512
#define A_  64
#define CV  448     // C - A (value / z_img dims)
#define G_  256
#define HW  256
#define SMX 256     // padded S (Smax)
#define BSP 8       // b-rows per block (2 blocks per group)

// ---------------- K1: spatial mean pool + per-group size ---------------------
__global__ __launch_bounds__(256) void meanpool_kernel(const float* __restrict__ Zimg,
                                                       float* __restrict__ z,
                                                       const int* __restrict__ pad_idx,
                                                       int* __restrict__ sgArr,
                                                       int Smax, int N) {
  const int bid = blockIdx.x, t = threadIdx.x;
  const int lane = t & 63, wave = t >> 6;
  __shared__ int r4[4];

  if (bid < G_) {                       // group size (prefix-contiguous validity)
    int v = pad_idx[(size_t)bid * Smax + t];
    bool ok = ((t == 0) || (v != 0)) && (v >= 0) && (v < N);
    int sgv = ok ? (t + 1) : 0;
    #pragma unroll
    for (int off = 32; off > 0; off >>= 1)
      sgv = max(sgv, __shfl_xor(sgv, off, 64));
    if (lane == 0) r4[wave] = sgv;
    __syncthreads();
    if (t == 0) sgArr[bid] = max(max(r4[0], r4[1]), max(r4[2], r4[3]));
  }

  int row = (bid << 2) + (t >> 6);      // b*C + c
  const float4* p = (const float4*)(Zimg + (size_t)row * HW);
  float4 v = p[lane];
  float s = (v.x + v.y) + (v.z + v.w);
  #pragma unroll
  for (int off = 32; off > 0; off >>= 1)
    s += __shfl_down(s, off, 64);
  if (lane == 0) z[row] = s * (1.0f / HW);
}

// ---------------- K2: bucket-rank groups by size (descending) ----------------
__global__ __launch_bounds__(256) void sched_kernel(const int* __restrict__ sgArr,
                                                    int* __restrict__ grank) {
  __shared__ int cnt[8], base[8];
  const int t = threadIdx.x;
  if (t < 8) cnt[t] = 0;
  __syncthreads();
  int sg = sgArr[t];
  int bk = min(7, max(0, sg - 32) >> 5);       // 32..256 -> 0..7
  atomicAdd(&cnt[bk], 1);
  __syncthreads();
  if (t == 0) {
    int o = 0;
    for (int b = 7; b >= 0; b--) { base[b] = o; o += cnt[b]; }
  }
  __syncthreads();
  int r = atomicAdd(&base[bk], 1);
  grank[r] = t;
}

// ---------------- K3: fused scores + softmax + PV + M_img --------------------
// Base = round-5 kernel (51us, VGPR 60, 0 conflicts). ONE change: Phase B's
// gather pipeline is FORCED to materialize. Evidence across r1/r6/r9: time
// ~= 1.2us x KB-per-wave regardless of occupancy/traffic/mapping, and r6's
// VGPR_Count=32 proves the compiler folded the v[8] load loop into the FMA
// loop (8 float4 = 32 VGPR alone) -> loads fully SERIAL per wave at ~L3
// latency each. Fix: hoist idx reads, issue 8 loads into NAMED v0..v7, then
// sched_barrier(0) -> all 8 live simultaneously, first FMA waits vmcnt(7)
// only. Expect VGPR ~90-110 (confirmation), per-iter ~L+compute not ~4L.
__global__ __launch_bounds__(512, 4) void fused_kernel(
    const float* __restrict__ Zsnd,
    const int*   __restrict__ pad_idx,
    const float* __restrict__ z,
    const int*   __restrict__ grank,
    float*       __restrict__ Mimg,
    float*       __restrict__ Msnd,
    int Smax, int N)
{
  const int bid  = blockIdx.x;
  const int p_   = bid & 127;
  const int bh   = (bid >> 7) & 1;
  const int rr   = (bid >> 8) ? (255 - p_) : p_;
  const int g    = grank[rr];
  const int b0   = bh * BSP;
  const int t    = threadIdx.x;
  const int lane = t & 63;
  const int wave = t >> 6;

  __shared__ float qs[BSP * A_];            // 2 KB
  __shared__ float attnT[SMX * BSP];        // 8 KB  [s][b-local]
  __shared__ int   idxs[SMX];               // 1 KB
  __shared__ float red[8 * BSP];
  __shared__ float red2[8 * BSP];
  __shared__ int   redi[8];
  __shared__ float redS[4 * BSP * 64 * 4];  // 32 KB [ch][b][lane] float4

  // ---- stage: validity/idx, queries, M_img broadcast ----
  int sgv = 0;
  if (t < SMX) {
    int v = pad_idx[(size_t)g * Smax + t];
    bool ok = ((t == 0) || (v != 0)) && (v >= 0) && (v < N);
    idxs[t] = ok ? v : 0;
    sgv = ok ? (t + 1) : 0;
  }
  #pragma unroll
  for (int off = 32; off > 0; off >>= 1)
    sgv = max(sgv, __shfl_xor(sgv, off, 64));
  if (lane == 0) redi[wave] = sgv;

  if (t < BSP * 16) {                       // 8 b x 16 a4 = 128 float4s
    int b = t >> 4, a4 = t & 15;
    *(float4*)(qs + b * A_ + a4 * 4) =
        *(const float4*)(z + (b0 + b) * C_ + CV + a4 * 4);
  }

  {                                         // Mimg[g, b0+b, :] = z[b0+b, :CV]
    int b = t >> 6, c = t & 63;
    float* mrow = Mimg + (size_t)g * (B_ * CV) + (b0 + b) * CV;
    const float* zrow = z + (b0 + b) * C_;
    *(float4*)(mrow + c * 4) = *(const float4*)(zrow + c * 4);
    int c2 = c + 64;
    if (c2 < 112)
      *(float4*)(mrow + c2 * 4) = *(const float4*)(zrow + c2 * 4);
  }

  __syncthreads();
  const int sg = max(max(max(redi[0], redi[1]), max(redi[2], redi[3])),
                     max(max(redi[4], redi[5]), max(redi[6], redi[7])));

  // ---- Phase A: scores (split-K over kh) ----
  const int s_ = t >> 1;
  const int kh = t & 1;
  const bool valid = (s_ < sg);             // prefix-contiguous validity
  const float* krow = Zsnd + (size_t)idxs[s_] * C_ + CV + kh * 32;

  float sc[BSP];
  #pragma unroll
  for (int b = 0; b < BSP; b++) sc[b] = 0.0f;

  #pragma unroll
  for (int c = 0; c < 2; c++) {
    float4 k0 = *(const float4*)(krow + c * 16 + 0);
    float4 k1 = *(const float4*)(krow + c * 16 + 4);
    float4 k2 = *(const float4*)(krow + c * 16 + 8);
    float4 k3 = *(const float4*)(krow + c * 16 + 12);
    #pragma unroll
    for (int b = 0; b < BSP; b++) {
      const float* qb = qs + b * A_ + kh * 32 + c * 16;
      float4 q0 = *(const float4*)(qb + 0);
      float4 q1 = *(const float4*)(qb + 4);
      float4 q2 = *(const float4*)(qb + 8);
      float4 q3 = *(const float4*)(qb + 12);
      sc[b] += q0.x * k0.x + q0.y * k0.y + q0.z * k0.z + q0.w * k0.w
             + q1.x * k1.x + q1.y * k1.y + q1.z * k1.z + q1.w * k1.w
             + q2.x * k2.x + q2.y * k2.y + q2.z * k2.z + q2.w * k2.w
             + q3.x * k3.x + q3.y * k3.y + q3.z * k3.z + q3.w * k3.w;
    }
    __builtin_amdgcn_sched_barrier(0);      // cap live values (anti-spill)
  }
  #pragma unroll
  for (int b = 0; b < BSP; b++)
    sc[b] += __shfl_xor(sc[b], 1, 64);      // combine kh halves: full dot

  // ---- softmax over s (butterfly within wave, LDS across 8 waves) ----
  #pragma unroll
  for (int b = 0; b < BSP; b++) {
    float v = valid ? sc[b] : -INFINITY;
    #pragma unroll
    for (int off = 32; off > 0; off >>= 1)
      v = fmaxf(v, __shfl_xor(v, off, 64));
    if (lane == 0) red[wave * BSP + b] = v;
  }
  __syncthreads();

  float ex[BSP];
  #pragma unroll
  for (int b = 0; b < BSP; b++) {
    float gm = red[0 * BSP + b];
    #pragma unroll
    for (int w2 = 1; w2 < 8; w2++) gm = fmaxf(gm, red[w2 * BSP + b]);
    float e = valid ? __expf(sc[b] - gm) : 0.0f;
    ex[b] = e;
    float es = (kh == 0) ? e : 0.0f;        // count each s once
    #pragma unroll
    for (int off = 32; off > 0; off >>= 1)
      es += __shfl_xor(es, off, 64);
    if (lane == 0) red2[wave * BSP + b] = es;
  }
  __syncthreads();

  if (kh == 0) {
    float iv[BSP];
    #pragma unroll
    for (int b = 0; b < BSP; b++) {
      float gs = red2[0 * BSP + b];
      #pragma unroll
      for (int w2 = 1; w2 < 8; w2++) gs += red2[w2 * BSP + b];
      iv[b] = ex[b] / gs;
    }
    *(float4*)(attnT + s_ * BSP + 0) = make_float4(iv[0], iv[1], iv[2], iv[3]);
    *(float4*)(attnT + s_ * BSP + 4) = make_float4(iv[4], iv[5], iv[6], iv[7]);
  }
  __syncthreads();

  // ---- Phase B: weighted value sum; FORCED 8-deep gather pipeline ----
  const int ch = wave >> 1;                 // column chunk (0..3)
  const int sh = wave & 1;                  // s parity
  const int cl = lane & 31;                 // float4 column slot
  const int h  = lane >> 5;                 // s sub-parity
  const int c0 = ch * 128;
  const int sg32 = (sg + 31) & ~31;         // attnT==0 past sg -> pad is exact

  const float* vbase = Zsnd + c0 + cl * 4;  // + idx*C_ ; col <= 508 in-row
  float4 acc[BSP];
  #pragma unroll
  for (int b = 0; b < BSP; b++) acc[b] = make_float4(0.f, 0.f, 0.f, 0.f);

  for (int s0 = 0; s0 < sg32; s0 += 32) {
    const int sb = s0 + 2 * sh + h;
    // hoisted LDS idx reads (batched ds_read, one lgkm wait)
    int i0 = idxs[sb +  0], i1 = idxs[sb +  4], i2 = idxs[sb +  8], i3 = idxs[sb + 12];
    int i4 = idxs[sb + 16], i5 = idxs[sb + 20], i6 = idxs[sb + 24], i7 = idxs[sb + 28];
    // 8 loads issued back-to-back into NAMED values; all live at the barrier
    float4 v0 = *(const float4*)(vbase + (size_t)i0 * C_);
    float4 v1 = *(const float4*)(vbase + (size_t)i1 * C_);
    float4 v2 = *(const float4*)(vbase + (size_t)i2 * C_);
    float4 v3 = *(const float4*)(vbase + (size_t)i3 * C_);
    float4 v4 = *(const float4*)(vbase + (size_t)i4 * C_);
    float4 v5 = *(const float4*)(vbase + (size_t)i5 * C_);
    float4 v6 = *(const float4*)(vbase + (size_t)i6 * C_);
    float4 v7 = *(const float4*)(vbase + (size_t)i7 * C_);
    __builtin_amdgcn_sched_barrier(0);      // loads may NOT sink past this
    #pragma unroll
    for (int j = 0; j < 8; j++) {
      float4 vv = (j == 0) ? v0 : (j == 1) ? v1 : (j == 2) ? v2 : (j == 3) ? v3
                : (j == 4) ? v4 : (j == 5) ? v5 : (j == 6) ? v6 : v7;
      int so = sb + 4 * j;
      float4 w0 = *(const float4*)(attnT + so * BSP + 0);   // b 0..3 (broadcast)
      float4 w1 = *(const float4*)(attnT + so * BSP + 4);   // b 4..7
      acc[0].x += w0.x * vv.x; acc[0].y += w0.x * vv.y; acc[0].z += w0.x * vv.z; acc[0].w += w0.x * vv.w;
      acc[1].x += w0.y * vv.x; acc[1].y += w0.y * vv.y; acc[1].z += w0.y * vv.z; acc[1].w += w0.y * vv.w;
      acc[2].x += w0.z * vv.x; acc[2].y += w0.z * vv.y; acc[2].z += w0.z * vv.z; acc[2].w += w0.z * vv.w;
      acc[3].x += w0.w * vv.x; acc[3].y += w0.w * vv.y; acc[3].z += w0.w * vv.z; acc[3].w += w0.w * vv.w;
      acc[4].x += w1.x * vv.x; acc[4].y += w1.x * vv.y; acc[4].z += w1.x * vv.z; acc[4].w += w1.x * vv.w;
      acc[5].x += w1.y * vv.x; acc[5].y += w1.y * vv.y; acc[5].z += w1.y * vv.z; acc[5].w += w1.y * vv.w;
      acc[6].x += w1.z * vv.x; acc[6].y += w1.z * vv.y; acc[6].z += w1.z * vv.z; acc[6].w += w1.z * vv.w;
      acc[7].x += w1.w * vv.x; acc[7].y += w1.w * vv.y; acc[7].z += w1.w * vv.z; acc[7].w += w1.w * vv.w;
    }
  }

  // ---- cross-wave combine: sh==1 partials -> LDS, sh==0 adds + h-shfl ----
  if (sh == 1) {
    #pragma unroll
    for (int b = 0; b < BSP; b++)
      *(float4*)(redS + (((size_t)ch * BSP + b) * 64 + lane) * 4) = acc[b];
  }
  __syncthreads();
  if (sh == 0) {
    #pragma unroll
    for (int b = 0; b < BSP; b++) {
      float4 o = *(const float4*)(redS + (((size_t)ch * BSP + b) * 64 + lane) * 4);
      acc[b].x += o.x; acc[b].y += o.y; acc[b].z += o.z; acc[b].w += o.w;
      acc[b].x += __shfl_xor(acc[b].x, 32, 64);
      acc[b].y += __shfl_xor(acc[b].y, 32, 64);
      acc[b].z += __shfl_xor(acc[b].z, 32, 64);
      acc[b].w += __shfl_xor(acc[b].w, 32, 64);
    }
    if (h == 0 && c0 + cl * 4 < CV) {
      float* obase = Msnd + (size_t)g * (B_ * CV) + (size_t)b0 * CV + c0 + cl * 4;
      #pragma unroll
      for (int b = 0; b < BSP; b++)
        *(float4*)(obase + b * CV) = acc[b];
    }
  }
}

extern "C" void kernel_launch(void* const* d_in, const int* in_sizes, int n_in,
                              void* d_out, int out_size, void* d_ws, size_t ws_size,
                              hipStream_t stream) {
  const float* Zimg   = (const float*)d_in[0];
  const float* Zsnd   = (const float*)d_in[1];
  const int*   padidx = (const int*)d_in[2];
  // d_in[3] = pad_mask (unused; validity derived from pad_idx)
  // d_in[4] = attn_dims (constant 64)

  const int N    = in_sizes[1] / C_;     // rows in Z_snd
  const int Smax = in_sizes[2] / G_;     // padded sequence length (== 256)

  float* z     = (float*)d_ws;                            // B*C fp32
  int*   sgArr = (int*)(z + B_ * C_);                     // 256 ints
  int*   grank = sgArr + G_;                              // 256 ints
  float* Mimg = (float*)d_out;
  float* Msnd = Mimg + (size_t)G_ * B_ * CV;

  meanpool_kernel<<<(B_ * C_) / 4, 256, 0, stream>>>(Zimg, z, padidx, sgArr, Smax, N);
  sched_kernel<<<1, 256, 0, stream>>>(sgArr, grank);
  fused_kernel<<<G_ * 2, 512, 0, stream>>>(Zsnd, padidx, z, grank, Mimg, Msnd, Smax, N);
}